// Round 12
// baseline (217.688 us; speedup 1.0000x reference)
//
#include <hip/hip_runtime.h>

// ---------------------------------------------------------------------------
// FactorizedSynthesizerRandom: B=8, S=2048, D=1024, K=8
//   q = x@Wq+bq, k = x@Wk+bk  (rank-8)
//   attn = softmax(q k^T)                        -> output[1] (f32, 8x2048x2048)
//   out  = attn @ (x@Wv+bv)                      -> output[0] (f32, 8x2048x1024)
// Round 12: round-9 restored (prep 4608, fused_gs) + gemm1 rewritten in the
// m97-class structure (128x128 tile, 4 waves, single-buffer 32KB LDS, 2
// syncthreads/K-tile) at 1024 blocks -> ~3 blocks/CU co-residency hides the
// barrier drains (the round-8 mechanism, applied to gemm1). attnF expansion
// rides in the K-loop (4 f32/thread/iter, drained by existing barriers).
// ---------------------------------------------------------------------------

typedef __attribute__((ext_vector_type(8))) __bf16 bf16x8;
typedef __attribute__((ext_vector_type(4))) __bf16 bf16x4;
typedef __attribute__((ext_vector_type(4))) float  f32x4;
typedef unsigned int u32;

#define GLB_CAST(p) ((const __attribute__((address_space(1))) u32*)(p))
#define LDS_CAST(p) ((__attribute__((address_space(3))) u32*)(p))

static constexpr int    Bn   = 8;
static constexpr int    S    = 2048;
static constexpr int    Dd   = 1024;
static constexpr int    Mtot = Bn * S;            // 16384
static constexpr size_t OUT0 = (size_t)Bn * S * Dd;

// workspace layout (bytes)
static constexpr size_t OFF_XBF  = 0;                                  // [16384][1024] bf16
static constexpr size_t OFF_WVT  = OFF_XBF + (size_t)Mtot * Dd * 2;    // [1024][1024] bf16 (Wv^T)
static constexpr size_t OFF_Q    = OFF_WVT + (size_t)Dd * Dd * 2;      // [16384][8] f32
static constexpr size_t OFF_K    = OFF_Q   + (size_t)Mtot * 8 * 4;     // [16384][8] f32
static constexpr size_t OFF_VT   = OFF_K   + (size_t)Mtot * 8 * 4;     // [8][1024][2048] bf16
static constexpr size_t OFF_ATTB = OFF_VT  + (size_t)Bn * Dd * S * 2;  // [8][2048][2048] bf16
static constexpr size_t WS_NEED  = OFF_ATTB + (size_t)Bn * S * S * 2;  // ~137 MB

// ---------------------------------------------------------------------------
// prep (round-9): [0,256): q/k projection from f32 x; [256,512): Wv->Wv^T;
//                 [512,4608): x f32 -> bf16.
// ---------------------------------------------------------------------------
__global__ __launch_bounds__(256) void prep_kernel(
    const float* __restrict__ x, const float* __restrict__ Wq,
    const float* __restrict__ Wk, const float* __restrict__ Wv,
    const float* __restrict__ bq, const float* __restrict__ bk,
    __bf16* __restrict__ xbf, __bf16* __restrict__ wvt,
    float* __restrict__ qb, float* __restrict__ kb)
{
    __shared__ float lt[64][65];
    int bid = blockIdx.x, t = threadIdx.x;
    if (bid < 256) {
        int l = t & 63, w = t >> 6;
        int mbase = (bid * 4 + w) * 16;
        int n = l & 15;
        int dbase = (l >> 4) << 3;
        const float* xr = x + (size_t)(mbase + n) * 1024 + dbase;
        const float* wcol = (n < 8) ? (Wq + n) : (Wk + (n & 7));
        f32x4 acc = {0.f, 0.f, 0.f, 0.f};
        #pragma unroll 4
        for (int kk = 0; kk < 1024; kk += 32) {
            f32x4 a0 = *(const f32x4*)(xr + kk);
            f32x4 a1 = *(const f32x4*)(xr + kk + 4);
            bf16x8 a, b;
            #pragma unroll
            for (int c = 0; c < 4; ++c) { a[c] = (__bf16)a0[c]; a[4 + c] = (__bf16)a1[c]; }
            #pragma unroll
            for (int u = 0; u < 8; ++u) b[u] = (__bf16)wcol[(size_t)(dbase + kk + u) * 8];
            acc = __builtin_amdgcn_mfma_f32_16x16x32_bf16(a, b, acc, 0, 0, 0);
        }
        float bias = (n < 8) ? bq[n] : bk[n & 7];
        #pragma unroll
        for (int r = 0; r < 4; ++r) {
            int m = mbase + ((l >> 4) << 2) + r;
            float v = acc[r] + bias;
            if (n < 8) qb[m * 8 + n] = v;
            else       kb[m * 8 + (n & 7)] = v;
        }
    } else if (bid < 512) {
        int tile = bid - 256;
        int tr = tile >> 4, tc = tile & 15;
        int r0 = t >> 6, c = t & 63;
        #pragma unroll
        for (int i = 0; i < 16; ++i) {
            int row = i * 4 + r0;
            lt[row][c] = Wv[(size_t)(tr * 64 + row) * 1024 + tc * 64 + c];
        }
        __syncthreads();
        #pragma unroll
        for (int i = 0; i < 16; ++i) {
            int er = i * 4 + r0;
            wvt[(size_t)(tc * 64 + er) * 1024 + tr * 64 + c] = (__bf16)lt[c][er];
        }
    } else {
        int bid2 = bid - 512;
        #pragma unroll
        for (int i = 0; i < 4; ++i) {
            size_t idx4 = (size_t)i * 1048576 + (size_t)bid2 * 256 + t;
            f32x4 v = ((const f32x4*)x)[idx4];
            bf16x4 o;
            #pragma unroll
            for (int c = 0; c < 4; ++c) o[c] = (__bf16)v[c];
            ((bf16x4*)xbf)[idx4] = o;
        }
    }
}

// ---------------------------------------------------------------------------
// fused gemm0 || softmax (round-9, unchanged). Grid 1536 x 256 threads.
// ---------------------------------------------------------------------------
__global__ __launch_bounds__(256) void fused_gs_kernel(
    const __bf16* __restrict__ xbf, const __bf16* __restrict__ wvt,
    const float* __restrict__ bv,
    const float* __restrict__ qb, const float* __restrict__ kb,
    __bf16* __restrict__ vtOut, __bf16* __restrict__ attnB)
{
    __shared__ __align__(1024) char smem[32768];
    __shared__ float redm[4], reds[4];
    int bid = blockIdx.x, t = threadIdx.x;
    int seg = bid >> 8;
    int gid = -1, sid = -1;
    if (seg == 0) gid = bid;
    else if (seg == 1) sid = bid - 256;
    else if (seg == 2) gid = bid - 256;
    else if (seg == 3) sid = bid - 512;
    else gid = bid - 512;                        // segs 4,5 -> gid 512..1023

    if (sid < 0) {
        // ================= gemm0 (m97-class) =================
        int g = ((gid & 7) << 7) | (gid >> 3);   // bijective XCD swizzle (1024)
        int mblk = g >> 3, nblk = g & 7;         // 128 x 8
        int l = t & 63, wid = t >> 6;
        int wmr = wid >> 1, wnc = wid & 1;       // 2(M) x 2(N) waves
        int lr = l & 15, lk = l >> 4;

        int srow = t >> 3;                       // 0..31
        int ssl  = (t & 7) ^ (srow & 7);
        const __bf16* gA = xbf + (size_t)(mblk * 128 + srow) * 1024 + ssl * 8;
        const __bf16* gB = wvt + (size_t)(nblk * 128 + srow) * 1024 + ssl * 8;

        int s0 = (lk ^ (lr & 7)) << 3;
        int s1 = ((lk ^ 4) ^ (lr & 7)) << 3;
        int offA0 = (wmr * 64 + lr) * 64 + s0;
        int offA1 = (wmr * 64 + lr) * 64 + s1;
        int offB0 = (wnc * 64 + lr) * 64 + s0;
        int offB1 = (wnc * 64 + lr) * 64 + s1;

        f32x4 acc[4][4] = {};

        for (int tt = 0; tt < 16; ++tt) {
            int kk = tt * 64;
            #pragma unroll
            for (int c = 0; c < 4; ++c) {
                __builtin_amdgcn_global_load_lds(
                    GLB_CAST(gA + (size_t)c * 32 * 1024 + kk),
                    LDS_CAST(smem + c * 4096 + wid * 1024), 16, 0, 0);
                __builtin_amdgcn_global_load_lds(
                    GLB_CAST(gB + (size_t)c * 32 * 1024 + kk),
                    LDS_CAST(smem + 16384 + c * 4096 + wid * 1024), 16, 0, 0);
            }
            __syncthreads();
            const __bf16* As = (const __bf16*)smem;
            const __bf16* Bs = (const __bf16*)(smem + 16384);
            bf16x8 af[4], bfr[4];
            #pragma unroll
            for (int i = 0; i < 4; ++i) af[i]  = *(const bf16x8*)(As + offA0 + i * 1024);
            #pragma unroll
            for (int j = 0; j < 4; ++j) bfr[j] = *(const bf16x8*)(Bs + offB0 + j * 1024);
            #pragma unroll
            for (int i = 0; i < 4; ++i)
                #pragma unroll
                for (int j = 0; j < 4; ++j)
                    acc[i][j] = __builtin_amdgcn_mfma_f32_16x16x32_bf16(af[i], bfr[j], acc[i][j], 0, 0, 0);
            #pragma unroll
            for (int i = 0; i < 4; ++i) af[i]  = *(const bf16x8*)(As + offA1 + i * 1024);
            #pragma unroll
            for (int j = 0; j < 4; ++j) bfr[j] = *(const bf16x8*)(Bs + offB1 + j * 1024);
            #pragma unroll
            for (int i = 0; i < 4; ++i)
                #pragma unroll
                for (int j = 0; j < 4; ++j)
                    acc[i][j] = __builtin_amdgcn_mfma_f32_16x16x32_bf16(af[i], bfr[j], acc[i][j], 0, 0, 0);
            __syncthreads();
        }

        #pragma unroll
        for (int j = 0; j < 4; ++j) {
            int e = (nblk << 7) + wnc * 64 + j * 16 + lr;
            float bias = bv[e];
            #pragma unroll
            for (int i = 0; i < 4; ++i) {
                int m0 = (mblk << 7) + wmr * 64 + i * 16 + (lk << 2);
                int b = m0 >> 11, sA = m0 & 2047;
                bf16x4 o;
                #pragma unroll
                for (int r = 0; r < 4; ++r) o[r] = (__bf16)(acc[i][j][r] + bias);
                *(bf16x4*)&vtOut[(((size_t)(b << 10) + e) << 11) + sA] = o;
            }
        }
    } else {
        // ================= softmax (attnB only) =================
        int b = sid >> 6, chunk = sid & 63;
        int l = t & 63, w = t >> 6;
        float kr[8][8];
        const float* kbb = kb + ((size_t)b << 14);
        #pragma unroll
        for (int jj = 0; jj < 8; ++jj) {
            f32x4 v0 = *(const f32x4*)(kbb + (size_t)(t * 8 + jj) * 8);
            f32x4 v1 = *(const f32x4*)(kbb + (size_t)(t * 8 + jj) * 8 + 4);
            #pragma unroll
            for (int c = 0; c < 4; ++c) { kr[jj][c] = v0[c]; kr[jj][4 + c] = v1[c]; }
        }
        const float* qrow = qb + ((size_t)b << 14);
        for (int ii = 0; ii < 32; ++ii) {
            int i = (chunk << 5) + ii;
            f32x4 q0 = *(const f32x4*)(qrow + (size_t)i * 8);
            f32x4 q1 = *(const f32x4*)(qrow + (size_t)i * 8 + 4);
            float e[8];
            #pragma unroll
            for (int jj = 0; jj < 8; ++jj) {
                float s = q0[0] * kr[jj][0];
                s = fmaf(q0[1], kr[jj][1], s);
                s = fmaf(q0[2], kr[jj][2], s);
                s = fmaf(q0[3], kr[jj][3], s);
                s = fmaf(q1[0], kr[jj][4], s);
                s = fmaf(q1[1], kr[jj][5], s);
                s = fmaf(q1[2], kr[jj][6], s);
                s = fmaf(q1[3], kr[jj][7], s);
                e[jj] = s;
            }
            float mx = e[0];
            #pragma unroll
            for (int jj = 1; jj < 8; ++jj) mx = fmaxf(mx, e[jj]);
            #pragma unroll
            for (int d = 1; d < 64; d <<= 1) mx = fmaxf(mx, __shfl_xor(mx, d));
            if (l == 0) redm[w] = mx;
            __syncthreads();
            mx = fmaxf(fmaxf(redm[0], redm[1]), fmaxf(redm[2], redm[3]));
            float p[8], sum = 0.f;
            #pragma unroll
            for (int jj = 0; jj < 8; ++jj) { p[jj] = __expf(e[jj] - mx); sum += p[jj]; }
            #pragma unroll
            for (int d = 1; d < 64; d <<= 1) sum += __shfl_xor(sum, d);
            if (l == 0) reds[w] = sum;
            __syncthreads();
            float T = (reds[0] + reds[1]) + (reds[2] + reds[3]);
            float inv = 1.0f / T;
            size_t off = (((size_t)b << 11) + i) * 2048 + (size_t)t * 8;
            bf16x8 ob;
            #pragma unroll
            for (int c = 0; c < 4; ++c) {
                ob[c] = (__bf16)(p[c] * inv); ob[4 + c] = (__bf16)(p[4 + c] * inv);
            }
            *(bf16x8*)(attnB + off) = ob;
        }
    }
}

// ---------------------------------------------------------------------------
// gemm1 (m97-class): out[b][m][e] f32 = attnB[b] @ vt[b]^T. 128x128 tile,
// 4 waves (2x2, 64x64 each), BK=64, NT=32, single-buffer 32KB LDS, XOR
// swizzle slot^=row&7 via pre-swizzled source, 2 syncthreads/K-tile.
// Grid 1024 = 8 batches x 128 tiles; XCD swizzle pins batch b to XCD b
// (vt panel 4MB = one L2). ~3 blocks/CU co-resident -> barrier drains
// overlap across blocks. attnF expansion rides the loop: each block owns
// rows mblk*128+nblk*16+[0,16); per iter, thread copies 4 f32 (load chunk
// tt, store chunk tt-1; drained by the existing syncthreads).
// ---------------------------------------------------------------------------
__global__ __launch_bounds__(256) void gemm1_kernel(
    const __bf16* __restrict__ A, const __bf16* __restrict__ Bt,
    float* __restrict__ outF, float* __restrict__ attnF)
{
    constexpr int NT = 32;
    __shared__ __align__(1024) char smem[32768];
    int bid = blockIdx.x, t = threadIdx.x;
    int g = ((bid & 7) << 7) | (bid >> 3);       // bijective XCD swizzle (1024)
    int bb = g >> 7;                             // batch -> XCD
    int tile = g & 127;
    int mblk = tile >> 3, nblk = tile & 7;       // 16(M) x 8(N)
    int l = t & 63, wid = t >> 6;
    int wmr = wid >> 1, wnc = wid & 1;           // 2(M) x 2(N) waves
    int lr = l & 15, lk = l >> 4;

    const __bf16* Ab = A  + (size_t)bb * S * S  + (size_t)(mblk * 128) * 2048;
    const __bf16* Bb = Bt + (size_t)bb * Dd * S + (size_t)(nblk * 128) * 2048;

    int srow = t >> 3;                           // 0..31
    int ssl  = (t & 7) ^ (srow & 7);
    const __bf16* gA = Ab + (size_t)srow * 2048 + ssl * 8;
    const __bf16* gB = Bb + (size_t)srow * 2048 + ssl * 8;

    int s0 = (lk ^ (lr & 7)) << 3;
    int s1 = ((lk ^ 4) ^ (lr & 7)) << 3;
    int offA0 = (wmr * 64 + lr) * 64 + s0;
    int offA1 = (wmr * 64 + lr) * 64 + s1;
    int offB0 = (wnc * 64 + lr) * 64 + s0;
    int offB1 = (wnc * 64 + lr) * 64 + s1;

    // attnF copy-role: row mblk*128 + nblk*16 + (t>>4), cols (t&15)*4 + tt*64
    int crow = mblk * 128 + nblk * 16 + (t >> 4);
    int ccol = (t & 15) * 4;
    const __bf16* cpSrc = A + (size_t)bb * S * S + (size_t)crow * 2048 + ccol;
    float* cpDst = attnF + ((size_t)bb << 22) + ((size_t)crow << 11) + ccol;
    bf16x4 pv;

    f32x4 acc[4][4] = {};

    for (int tt = 0; tt < NT; ++tt) {
        int kk = tt * 64;
        #pragma unroll
        for (int c = 0; c < 4; ++c) {
            __builtin_amdgcn_global_load_lds(
                GLB_CAST(gA + (size_t)c * 32 * 2048 + kk),
                LDS_CAST(smem + c * 4096 + wid * 1024), 16, 0, 0);
            __builtin_amdgcn_global_load_lds(
                GLB_CAST(gB + (size_t)c * 32 * 2048 + kk),
                LDS_CAST(smem + 16384 + c * 4096 + wid * 1024), 16, 0, 0);
        }
        // attnF expansion: store chunk tt-1 (regs), load chunk tt
        if (tt >= 1) {
            f32x4 cv;
            #pragma unroll
            for (int c = 0; c < 4; ++c) cv[c] = (float)pv[c];
            *(f32x4*)(cpDst + (tt - 1) * 64) = cv;
        }
        pv = *(const bf16x4*)(cpSrc + tt * 64);
        __syncthreads();                          // drains staging + copy load
        const __bf16* As = (const __bf16*)smem;
        const __bf16* Bs = (const __bf16*)(smem + 16384);
        bf16x8 af[4], bfr[4];
        #pragma unroll
        for (int i = 0; i < 4; ++i) af[i]  = *(const bf16x8*)(As + offA0 + i * 1024);
        #pragma unroll
        for (int j = 0; j < 4; ++j) bfr[j] = *(const bf16x8*)(Bs + offB0 + j * 1024);
        #pragma unroll
        for (int i = 0; i < 4; ++i)
            #pragma unroll
            for (int j = 0; j < 4; ++j)
                acc[i][j] = __builtin_amdgcn_mfma_f32_16x16x32_bf16(af[i], bfr[j], acc[i][j], 0, 0, 0);
        #pragma unroll
        for (int i = 0; i < 4; ++i) af[i]  = *(const bf16x8*)(As + offA1 + i * 1024);
        #pragma unroll
        for (int j = 0; j < 4; ++j) bfr[j] = *(const bf16x8*)(Bs + offB1 + j * 1024);
        #pragma unroll
        for (int i = 0; i < 4; ++i)
            #pragma unroll
            for (int j = 0; j < 4; ++j)
                acc[i][j] = __builtin_amdgcn_mfma_f32_16x16x32_bf16(af[i], bfr[j], acc[i][j], 0, 0, 0);
        __syncthreads();                          // all reads done before overwrite
    }

    // final attnF chunk
    {
        f32x4 cv;
        #pragma unroll
        for (int c = 0; c < 4; ++c) cv[c] = (float)pv[c];
        *(f32x4*)(cpDst + (NT - 1) * 64) = cv;
    }

    float* ob = outF + (size_t)bb * S * Dd;
    #pragma unroll
    for (int i = 0; i < 4; ++i) {
        int m0 = (mblk << 7) + wmr * 64 + i * 16 + (lk << 2);
        #pragma unroll
        for (int j = 0; j < 4; ++j) {
            int e = (nblk << 7) + wnc * 64 + j * 16 + lr;
            #pragma unroll
            for (int r = 0; r < 4; ++r)
                ob[(size_t)(m0 + r) * 1024 + e] = acc[i][j][r];
        }
    }
}

// ---------------------------------------------------------------------------
extern "C" void kernel_launch(void* const* d_in, const int* in_sizes, int n_in,
                              void* d_out, int out_size, void* d_ws, size_t ws_size,
                              hipStream_t stream)
{
    const float* x  = (const float*)d_in[0];
    const float* Wq = (const float*)d_in[1];
    const float* bq = (const float*)d_in[2];
    const float* Wk = (const float*)d_in[3];
    const float* bk = (const float*)d_in[4];
    const float* Wv = (const float*)d_in[5];
    const float* bv = (const float*)d_in[6];

    float* outp  = (float*)d_out;
    float* attnF = outp + OUT0;

    if (ws_size < WS_NEED) return;
    char* ws = (char*)d_ws;
    __bf16* xbf   = (__bf16*)(ws + OFF_XBF);
    __bf16* wvt   = (__bf16*)(ws + OFF_WVT);
    float*  qbuf  = (float*)(ws + OFF_Q);
    float*  kbuf  = (float*)(ws + OFF_K);
    __bf16* vt    = (__bf16*)(ws + OFF_VT);
    __bf16* attnB = (__bf16*)(ws + OFF_ATTB);

    prep_kernel<<<4608, 256, 0, stream>>>(x, Wq, Wk, Wv, bq, bk, xbf, wvt, qbuf, kbuf);
    fused_gs_kernel<<<1536, 256, 0, stream>>>(xbf, wvt, bv, qbuf, kbuf, vt, attnB);
    gemm1_kernel<<<1024, 256, 0, stream>>>(attnB, vt, outp, attnF);
}

// Round 13
// 213.726 us; speedup vs baseline: 1.0185x; 1.0185x over previous
//
#include <hip/hip_runtime.h>

// ---------------------------------------------------------------------------
// FactorizedSynthesizerRandom: B=8, S=2048, D=1024, K=8
//   q = x@Wq+bq, k = x@Wk+bk  (rank-8)
//   attn = softmax(q k^T)                        -> output[1] (f32, 8x2048x2048)
//   out  = attn @ (x@Wv+bv)                      -> output[0] (f32, 8x2048x1024)
// Round 13: round-9 restored (best, 185.7us; round-12's m97-gemm1 regressed —
// role-diversity, not multiplicity, is what hides barrier drains). One tweak:
// fused_gs role map changed from 256-block segments (tail = 512 pure-gemm
// blocks, no overlap partners) to mod-3 interleave so every CU holds
// ~2 gemm + 1 softmax block for the whole dispatch.
// ---------------------------------------------------------------------------

typedef __attribute__((ext_vector_type(8))) __bf16 bf16x8;
typedef __attribute__((ext_vector_type(4))) __bf16 bf16x4;
typedef __attribute__((ext_vector_type(4))) float  f32x4;
typedef unsigned int u32;

#define GLB_CAST(p) ((const __attribute__((address_space(1))) u32*)(p))
#define LDS_CAST(p) ((__attribute__((address_space(3))) u32*)(p))

#define S_BARRIER() { __builtin_amdgcn_s_barrier(); __builtin_amdgcn_sched_barrier(0); }
#define LGKM0()     { asm volatile("s_waitcnt lgkmcnt(0)" ::: "memory"); __builtin_amdgcn_sched_barrier(0); }
#define VMCNT9()    { asm volatile("s_waitcnt vmcnt(9)" ::: "memory"); __builtin_amdgcn_sched_barrier(0); }
#define VMCNT8()    { asm volatile("s_waitcnt vmcnt(8)" ::: "memory"); __builtin_amdgcn_sched_barrier(0); }
#define VMCNT0()    { asm volatile("s_waitcnt vmcnt(0)" ::: "memory"); __builtin_amdgcn_sched_barrier(0); }

static constexpr int    Bn   = 8;
static constexpr int    S    = 2048;
static constexpr int    Dd   = 1024;
static constexpr int    Mtot = Bn * S;            // 16384
static constexpr size_t OUT0 = (size_t)Bn * S * Dd;

// workspace layout (bytes)
static constexpr size_t OFF_XBF  = 0;                                  // [16384][1024] bf16
static constexpr size_t OFF_WVT  = OFF_XBF + (size_t)Mtot * Dd * 2;    // [1024][1024] bf16 (Wv^T)
static constexpr size_t OFF_Q    = OFF_WVT + (size_t)Dd * Dd * 2;      // [16384][8] f32
static constexpr size_t OFF_K    = OFF_Q   + (size_t)Mtot * 8 * 4;     // [16384][8] f32
static constexpr size_t OFF_VT   = OFF_K   + (size_t)Mtot * 8 * 4;     // [8][1024][2048] bf16
static constexpr size_t OFF_ATTB = OFF_VT  + (size_t)Bn * Dd * S * 2;  // [8][2048][2048] bf16
static constexpr size_t WS_NEED  = OFF_ATTB + (size_t)Bn * S * S * 2;  // ~137 MB

// ---------------------------------------------------------------------------
// prep (round-9): [0,256): q/k projection from f32 x; [256,512): Wv->Wv^T;
//                 [512,4608): x f32 -> bf16.
// ---------------------------------------------------------------------------
__global__ __launch_bounds__(256) void prep_kernel(
    const float* __restrict__ x, const float* __restrict__ Wq,
    const float* __restrict__ Wk, const float* __restrict__ Wv,
    const float* __restrict__ bq, const float* __restrict__ bk,
    __bf16* __restrict__ xbf, __bf16* __restrict__ wvt,
    float* __restrict__ qb, float* __restrict__ kb)
{
    __shared__ float lt[64][65];
    int bid = blockIdx.x, t = threadIdx.x;
    if (bid < 256) {
        int l = t & 63, w = t >> 6;
        int mbase = (bid * 4 + w) * 16;
        int n = l & 15;
        int dbase = (l >> 4) << 3;
        const float* xr = x + (size_t)(mbase + n) * 1024 + dbase;
        const float* wcol = (n < 8) ? (Wq + n) : (Wk + (n & 7));
        f32x4 acc = {0.f, 0.f, 0.f, 0.f};
        #pragma unroll 4
        for (int kk = 0; kk < 1024; kk += 32) {
            f32x4 a0 = *(const f32x4*)(xr + kk);
            f32x4 a1 = *(const f32x4*)(xr + kk + 4);
            bf16x8 a, b;
            #pragma unroll
            for (int c = 0; c < 4; ++c) { a[c] = (__bf16)a0[c]; a[4 + c] = (__bf16)a1[c]; }
            #pragma unroll
            for (int u = 0; u < 8; ++u) b[u] = (__bf16)wcol[(size_t)(dbase + kk + u) * 8];
            acc = __builtin_amdgcn_mfma_f32_16x16x32_bf16(a, b, acc, 0, 0, 0);
        }
        float bias = (n < 8) ? bq[n] : bk[n & 7];
        #pragma unroll
        for (int r = 0; r < 4; ++r) {
            int m = mbase + ((l >> 4) << 2) + r;
            float v = acc[r] + bias;
            if (n < 8) qb[m * 8 + n] = v;
            else       kb[m * 8 + (n & 7)] = v;
        }
    } else if (bid < 512) {
        int tile = bid - 256;
        int tr = tile >> 4, tc = tile & 15;
        int r0 = t >> 6, c = t & 63;
        #pragma unroll
        for (int i = 0; i < 16; ++i) {
            int row = i * 4 + r0;
            lt[row][c] = Wv[(size_t)(tr * 64 + row) * 1024 + tc * 64 + c];
        }
        __syncthreads();
        #pragma unroll
        for (int i = 0; i < 16; ++i) {
            int er = i * 4 + r0;
            wvt[(size_t)(tc * 64 + er) * 1024 + tr * 64 + c] = (__bf16)lt[c][er];
        }
    } else {
        int bid2 = bid - 512;
        #pragma unroll
        for (int i = 0; i < 4; ++i) {
            size_t idx4 = (size_t)i * 1048576 + (size_t)bid2 * 256 + t;
            f32x4 v = ((const f32x4*)x)[idx4];
            bf16x4 o;
            #pragma unroll
            for (int c = 0; c < 4; ++c) o[c] = (__bf16)v[c];
            ((bf16x4*)xbf)[idx4] = o;
        }
    }
}

// ---------------------------------------------------------------------------
// fused gemm0 || softmax. Grid 1536 x 256 threads.
// Role map: bid%3==1 -> softmax (sid=bid/3, 512 blocks); else gemm
// (gid=2*(bid/3)+(bid%3==2), 1024 blocks) — every CU holds ~2G+1S
// throughout the dispatch (round-8/9 mechanism, tail fixed).
// ---------------------------------------------------------------------------
__global__ __launch_bounds__(256) void fused_gs_kernel(
    const __bf16* __restrict__ xbf, const __bf16* __restrict__ wvt,
    const float* __restrict__ bv,
    const float* __restrict__ qb, const float* __restrict__ kb,
    __bf16* __restrict__ vtOut, __bf16* __restrict__ attnB)
{
    __shared__ __align__(1024) char smem[32768];
    __shared__ float redm[4], reds[4];
    int bid = blockIdx.x, t = threadIdx.x;
    int m3 = bid % 3, b3 = bid / 3;
    int gid = -1, sid = -1;
    if (m3 == 1) sid = b3;                       // 512 softmax blocks
    else gid = b3 * 2 + (m3 == 2 ? 1 : 0);       // 1024 gemm blocks

    if (sid < 0) {
        // ================= gemm0 (m97-class) =================
        int g = ((gid & 7) << 7) | (gid >> 3);   // bijective XCD swizzle (1024)
        int mblk = g >> 3, nblk = g & 7;         // 128 x 8
        int l = t & 63, wid = t >> 6;
        int wmr = wid >> 1, wnc = wid & 1;       // 2(M) x 2(N) waves
        int lr = l & 15, lk = l >> 4;

        int srow = t >> 3;                       // 0..31
        int ssl  = (t & 7) ^ (srow & 7);
        const __bf16* gA = xbf + (size_t)(mblk * 128 + srow) * 1024 + ssl * 8;
        const __bf16* gB = wvt + (size_t)(nblk * 128 + srow) * 1024 + ssl * 8;

        int s0 = (lk ^ (lr & 7)) << 3;
        int s1 = ((lk ^ 4) ^ (lr & 7)) << 3;
        int offA0 = (wmr * 64 + lr) * 64 + s0;
        int offA1 = (wmr * 64 + lr) * 64 + s1;
        int offB0 = (wnc * 64 + lr) * 64 + s0;
        int offB1 = (wnc * 64 + lr) * 64 + s1;

        f32x4 acc[4][4] = {};

        for (int tt = 0; tt < 16; ++tt) {
            int kk = tt * 64;
            #pragma unroll
            for (int c = 0; c < 4; ++c) {
                __builtin_amdgcn_global_load_lds(
                    GLB_CAST(gA + (size_t)c * 32 * 1024 + kk),
                    LDS_CAST(smem + c * 4096 + wid * 1024), 16, 0, 0);
                __builtin_amdgcn_global_load_lds(
                    GLB_CAST(gB + (size_t)c * 32 * 1024 + kk),
                    LDS_CAST(smem + 16384 + c * 4096 + wid * 1024), 16, 0, 0);
            }
            __syncthreads();
            const __bf16* As = (const __bf16*)smem;
            const __bf16* Bs = (const __bf16*)(smem + 16384);
            bf16x8 af[4], bfr[4];
            #pragma unroll
            for (int i = 0; i < 4; ++i) af[i]  = *(const bf16x8*)(As + offA0 + i * 1024);
            #pragma unroll
            for (int j = 0; j < 4; ++j) bfr[j] = *(const bf16x8*)(Bs + offB0 + j * 1024);
            #pragma unroll
            for (int i = 0; i < 4; ++i)
                #pragma unroll
                for (int j = 0; j < 4; ++j)
                    acc[i][j] = __builtin_amdgcn_mfma_f32_16x16x32_bf16(af[i], bfr[j], acc[i][j], 0, 0, 0);
            #pragma unroll
            for (int i = 0; i < 4; ++i) af[i]  = *(const bf16x8*)(As + offA1 + i * 1024);
            #pragma unroll
            for (int j = 0; j < 4; ++j) bfr[j] = *(const bf16x8*)(Bs + offB1 + j * 1024);
            #pragma unroll
            for (int i = 0; i < 4; ++i)
                #pragma unroll
                for (int j = 0; j < 4; ++j)
                    acc[i][j] = __builtin_amdgcn_mfma_f32_16x16x32_bf16(af[i], bfr[j], acc[i][j], 0, 0, 0);
            __syncthreads();
        }

        #pragma unroll
        for (int j = 0; j < 4; ++j) {
            int e = (nblk << 7) + wnc * 64 + j * 16 + lr;
            float bias = bv[e];
            #pragma unroll
            for (int i = 0; i < 4; ++i) {
                int m0 = (mblk << 7) + wmr * 64 + i * 16 + (lk << 2);
                int b = m0 >> 11, sA = m0 & 2047;
                bf16x4 o;
                #pragma unroll
                for (int r = 0; r < 4; ++r) o[r] = (__bf16)(acc[i][j][r] + bias);
                *(bf16x4*)&vtOut[(((size_t)(b << 10) + e) << 11) + sA] = o;
            }
        }
    } else {
        // ================= softmax (attnB only) =================
        int b = sid >> 6, chunk = sid & 63;
        int l = t & 63, w = t >> 6;
        float kr[8][8];
        const float* kbb = kb + ((size_t)b << 14);
        #pragma unroll
        for (int jj = 0; jj < 8; ++jj) {
            f32x4 v0 = *(const f32x4*)(kbb + (size_t)(t * 8 + jj) * 8);
            f32x4 v1 = *(const f32x4*)(kbb + (size_t)(t * 8 + jj) * 8 + 4);
            #pragma unroll
            for (int c = 0; c < 4; ++c) { kr[jj][c] = v0[c]; kr[jj][4 + c] = v1[c]; }
        }
        const float* qrow = qb + ((size_t)b << 14);
        for (int ii = 0; ii < 32; ++ii) {
            int i = (chunk << 5) + ii;
            f32x4 q0 = *(const f32x4*)(qrow + (size_t)i * 8);
            f32x4 q1 = *(const f32x4*)(qrow + (size_t)i * 8 + 4);
            float e[8];
            #pragma unroll
            for (int jj = 0; jj < 8; ++jj) {
                float s = q0[0] * kr[jj][0];
                s = fmaf(q0[1], kr[jj][1], s);
                s = fmaf(q0[2], kr[jj][2], s);
                s = fmaf(q0[3], kr[jj][3], s);
                s = fmaf(q1[0], kr[jj][4], s);
                s = fmaf(q1[1], kr[jj][5], s);
                s = fmaf(q1[2], kr[jj][6], s);
                s = fmaf(q1[3], kr[jj][7], s);
                e[jj] = s;
            }
            float mx = e[0];
            #pragma unroll
            for (int jj = 1; jj < 8; ++jj) mx = fmaxf(mx, e[jj]);
            #pragma unroll
            for (int d = 1; d < 64; d <<= 1) mx = fmaxf(mx, __shfl_xor(mx, d));
            if (l == 0) redm[w] = mx;
            __syncthreads();
            mx = fmaxf(fmaxf(redm[0], redm[1]), fmaxf(redm[2], redm[3]));
            float p[8], sum = 0.f;
            #pragma unroll
            for (int jj = 0; jj < 8; ++jj) { p[jj] = __expf(e[jj] - mx); sum += p[jj]; }
            #pragma unroll
            for (int d = 1; d < 64; d <<= 1) sum += __shfl_xor(sum, d);
            if (l == 0) reds[w] = sum;
            __syncthreads();
            float T = (reds[0] + reds[1]) + (reds[2] + reds[3]);
            float inv = 1.0f / T;
            size_t off = (((size_t)b << 11) + i) * 2048 + (size_t)t * 8;
            bf16x8 ob;
            #pragma unroll
            for (int c = 0; c < 4; ++c) {
                ob[c] = (__bf16)(p[c] * inv); ob[4 + c] = (__bf16)(p[4 + c] * inv);
            }
            *(bf16x8*)(attnB + off) = ob;
        }
    }
}

// ---------------------------------------------------------------------------
// gemm1 (round-9: 8-phase, 16x16x32) + interleaved attnB->attnF f32 expansion.
// vmcnt boundaries: tt==0 -> 8, tt>=1 -> 9 (8 staging + 1 copy-load).
// ---------------------------------------------------------------------------
__device__ __forceinline__ void g1_stageA(const __bf16* Ab, char* smem,
    int slot, int kk, int c, int rowin, int sl8, int wid)
{
    __builtin_amdgcn_global_load_lds(
        GLB_CAST(Ab + (size_t)(c * 64 + rowin) * 2048 + kk + sl8 * 8),
        LDS_CAST(smem + slot * 65536 + c * 8192 + wid * 1024), 16, 0, 0);
}
__device__ __forceinline__ void g1_stageB(const __bf16* Bb, char* smem,
    int slot, int kk, int c, int rowin, int sl8, int wid)
{
    __builtin_amdgcn_global_load_lds(
        GLB_CAST(Bb + (size_t)(c * 64 + rowin) * 2048 + kk + sl8 * 8),
        LDS_CAST(smem + slot * 65536 + 32768 + c * 8192 + wid * 1024), 16, 0, 0);
}

__global__ __launch_bounds__(512, 2) void gemm1_kernel(
    const __bf16* __restrict__ A, const __bf16* __restrict__ Bt,
    float* __restrict__ outF, float* __restrict__ attnF)
{
    constexpr int NT = 32;
    __shared__ __align__(1024) char smem[131072];

    int bid = blockIdx.x;
    int wg = ((bid & 7) << 5) | (bid >> 3);     // bijective XCD swizzle (nwg=256)
    int t = threadIdx.x, l = t & 63;
    int wid = t >> 6;
    int wmr = wid >> 2, wnc = wid & 3;

    int bb = wg >> 5; int r = wg & 31;          // one batch per XCD
    int mblk = r >> 2, nblk = r & 3;
    const __bf16* Ab = A + (size_t)bb * S * S + (size_t)mblk * 256 * 2048;
    const __bf16* Bb = Bt + (size_t)bb * Dd * S + (size_t)nblk * 256 * 2048;

    int rowin = t >> 3;
    int sl8 = (t & 7) ^ (rowin & 7);
    int lr = l & 15, lk = l >> 4;

    // attnF copy-role: row slice nblk*64 + (t>>3), col chunk (t&7)*8
    int crow = nblk * 64 + (t >> 3);
    int ccol = (t & 7) * 8;
    const __bf16* cpSrc = Ab + (size_t)crow * 2048 + ccol;
    float* cpDst = attnF + ((size_t)bb << 22) + ((size_t)(mblk * 256 + crow) << 11) + ccol;
    bf16x8 pv;

    f32x4 acc[8][4] = {};

    #pragma unroll
    for (int c = 0; c < 4; ++c) {
        g1_stageA(Ab, smem, 0, 0, c, rowin, sl8, wid);
        g1_stageB(Bb, smem, 0, 0, c, rowin, sl8, wid);
    }
    #pragma unroll
    for (int c = 0; c < 4; ++c) {
        g1_stageA(Ab, smem, 1, 64, c, rowin, sl8, wid);
        g1_stageB(Bb, smem, 1, 64, c, rowin, sl8, wid);
    }
    VMCNT8();
    S_BARRIER();

    for (int tt = 0; tt < NT; ++tt) {
        int s = tt & 1;
        const __bf16* Asl = (const __bf16*)(smem + s * 65536);
        const __bf16* Bsl = (const __bf16*)(smem + s * 65536 + 32768);
        bool pf = (tt + 2 < NT);
        int kk2 = (tt + 2) * 64;

        // ---- interleaved attnF copy: store chunk tt-2, load chunk tt-1
        if (tt >= 2) {
            f32x4 c0, c1;
            #pragma unroll
            for (int c = 0; c < 4; ++c) { c0[c] = (float)pv[c]; c1[c] = (float)pv[4 + c]; }
            *(f32x4*)(cpDst + (tt - 2) * 64) = c0;
            *(f32x4*)(cpDst + (tt - 2) * 64 + 4) = c1;
        }
        if (tt >= 1) {
            pv = *(const bf16x8*)(cpSrc + (tt - 1) * 64);
        }

        bf16x8 aLo[2][4], aHi[2][4], bLo[2][2], bHi[2][2];

        // ---- P0
        #pragma unroll
        for (int ks = 0; ks < 2; ++ks) {
            int sa = ks * 4 + lk;
            #pragma unroll
            for (int i = 0; i < 4; ++i) {
                int ra = wmr * 128 + i * 16 + lr;
                aLo[ks][i] = *(const bf16x8*)&Asl[ra * 64 + ((sa ^ (ra & 7)) << 3)];
            }
            #pragma unroll
            for (int j = 0; j < 2; ++j) {
                int rb = wnc * 64 + j * 16 + lr;
                bLo[ks][j] = *(const bf16x8*)&Bsl[rb * 64 + ((sa ^ (rb & 7)) << 3)];
            }
        }
        S_BARRIER(); LGKM0();
        __builtin_amdgcn_s_setprio(1);
        #pragma unroll
        for (int ks = 0; ks < 2; ++ks)
            #pragma unroll
            for (int i = 0; i < 4; ++i)
                #pragma unroll
                for (int j = 0; j < 2; ++j)
                    acc[i][j] = __builtin_amdgcn_mfma_f32_16x16x32_bf16(aLo[ks][i], bLo[ks][j], acc[i][j], 0, 0, 0);
        __builtin_amdgcn_s_setprio(0);
        S_BARRIER();

        // ---- P1
        #pragma unroll
        for (int ks = 0; ks < 2; ++ks) {
            int sa = ks * 4 + lk;
            #pragma unroll
            for (int j = 0; j < 2; ++j) {
                int rb = wnc * 64 + (j + 2) * 16 + lr;
                bHi[ks][j] = *(const bf16x8*)&Bsl[rb * 64 + ((sa ^ (rb & 7)) << 3)];
            }
        }
        if (pf) {
            g1_stageA(Ab, smem, s, kk2, 0, rowin, sl8, wid);
            g1_stageA(Ab, smem, s, kk2, 2, rowin, sl8, wid);
        }
        S_BARRIER(); LGKM0();
        __builtin_amdgcn_s_setprio(1);
        #pragma unroll
        for (int ks = 0; ks < 2; ++ks)
            #pragma unroll
            for (int i = 0; i < 4; ++i)
                #pragma unroll
                for (int j = 0; j < 2; ++j)
                    acc[i][2 + j] = __builtin_amdgcn_mfma_f32_16x16x32_bf16(aLo[ks][i], bHi[ks][j], acc[i][2 + j], 0, 0, 0);
        __builtin_amdgcn_s_setprio(0);
        S_BARRIER();

        // ---- P2
        #pragma unroll
        for (int ks = 0; ks < 2; ++ks) {
            int sa = ks * 4 + lk;
            #pragma unroll
            for (int i = 0; i < 4; ++i) {
                int ra = wmr * 128 + (i + 4) * 16 + lr;
                aHi[ks][i] = *(const bf16x8*)&Asl[ra * 64 + ((sa ^ (ra & 7)) << 3)];
            }
        }
        if (pf) {
            #pragma unroll
            for (int c = 0; c < 4; ++c)
                g1_stageB(Bb, smem, s, kk2, c, rowin, sl8, wid);
        }
        S_BARRIER(); LGKM0();
        __builtin_amdgcn_s_setprio(1);
        #pragma unroll
        for (int ks = 0; ks < 2; ++ks)
            #pragma unroll
            for (int i = 0; i < 4; ++i)
                #pragma unroll
                for (int j = 0; j < 2; ++j)
                    acc[4 + i][2 + j] = __builtin_amdgcn_mfma_f32_16x16x32_bf16(aHi[ks][i], bHi[ks][j], acc[4 + i][2 + j], 0, 0, 0);
        __builtin_amdgcn_s_setprio(0);
        S_BARRIER();

        // ---- P3
        if (pf) {
            g1_stageA(Ab, smem, s, kk2, 1, rowin, sl8, wid);
            g1_stageA(Ab, smem, s, kk2, 3, rowin, sl8, wid);
        }
        S_BARRIER();
        __builtin_amdgcn_s_setprio(1);
        #pragma unroll
        for (int ks = 0; ks < 2; ++ks)
            #pragma unroll
            for (int i = 0; i < 4; ++i)
                #pragma unroll
                for (int j = 0; j < 2; ++j)
                    acc[4 + i][j] = __builtin_amdgcn_mfma_f32_16x16x32_bf16(aHi[ks][i], bLo[ks][j], acc[4 + i][j], 0, 0, 0);
        __builtin_amdgcn_s_setprio(0);

        if (tt == NT - 1) break;
        S_BARRIER();
        if (pf) {
            if (tt == 0) { VMCNT8(); } else { VMCNT9(); }
        } else {
            VMCNT0();
        }
        S_BARRIER();
    }

    // ---- finish attnF chunks NT-2 (in pv) and NT-1
    {
        f32x4 c0, c1;
        #pragma unroll
        for (int c = 0; c < 4; ++c) { c0[c] = (float)pv[c]; c1[c] = (float)pv[4 + c]; }
        *(f32x4*)(cpDst + (NT - 2) * 64) = c0;
        *(f32x4*)(cpDst + (NT - 2) * 64 + 4) = c1;
        bf16x8 lastv = *(const bf16x8*)(cpSrc + (NT - 1) * 64);
        #pragma unroll
        for (int c = 0; c < 4; ++c) { c0[c] = (float)lastv[c]; c1[c] = (float)lastv[4 + c]; }
        *(f32x4*)(cpDst + (NT - 1) * 64) = c0;
        *(f32x4*)(cpDst + (NT - 1) * 64 + 4) = c1;
    }

    float* ob = outF + (size_t)bb * S * Dd;
    #pragma unroll
    for (int i = 0; i < 8; ++i) {
        int m0 = (mblk << 8) + wmr * 128 + i * 16 + (lk << 2);
        #pragma unroll
        for (int j = 0; j < 4; ++j) {
            int e = (nblk << 8) + wnc * 64 + j * 16 + lr;
            #pragma unroll
            for (int r = 0; r < 4; ++r)
                ob[(size_t)(m0 + r) * 1024 + e] = acc[i][j][r];
        }
    }
}

// ---------------------------------------------------------------------------
extern "C" void kernel_launch(void* const* d_in, const int* in_sizes, int n_in,
                              void* d_out, int out_size, void* d_ws, size_t ws_size,
                              hipStream_t stream)
{
    const float* x  = (const float*)d_in[0];
    const float* Wq = (const float*)d_in[1];
    const float* bq = (const float*)d_in[2];
    const float* Wk = (const float*)d_in[3];
    const float* bk = (const float*)d_in[4];
    const float* Wv = (const float*)d_in[5];
    const float* bv = (const float*)d_in[6];

    float* outp  = (float*)d_out;
    float* attnF = outp + OUT0;

    if (ws_size < WS_NEED) return;
    char* ws = (char*)d_ws;
    __bf16* xbf   = (__bf16*)(ws + OFF_XBF);
    __bf16* wvt   = (__bf16*)(ws + OFF_WVT);
    float*  qbuf  = (float*)(ws + OFF_Q);
    float*  kbuf  = (float*)(ws + OFF_K);
    __bf16* vt    = (__bf16*)(ws + OFF_VT);
    __bf16* attnB = (__bf16*)(ws + OFF_ATTB);

    prep_kernel<<<4608, 256, 0, stream>>>(x, Wq, Wk, Wv, bq, bk, xbf, wvt, qbuf, kbuf);
    fused_gs_kernel<<<1536, 256, 0, stream>>>(xbf, wvt, bv, qbuf, kbuf, vt, attnB);
    gemm1_kernel<<<256, 512, 0, stream>>>(attnB, vt, outp, attnF);
}

// Round 14
// 193.576 us; speedup vs baseline: 1.1246x; 1.1041x over previous
//
#include <hip/hip_runtime.h>

// ---------------------------------------------------------------------------
// FactorizedSynthesizerRandom: B=8, S=2048, D=1024, K=8
//   q = x@Wq+bq, k = x@Wk+bk  (rank-8)
//   attn = softmax(q k^T)                        -> output[1] (f32, 8x2048x2048)
//   out  = attn @ (x@Wv+bv)                      -> output[0] (f32, 8x2048x1024)
// Round 14: round-9 restored VERBATIM (best measured: 185.7us). Rounds 10-13
// explored MFMA shape (32x32: dep-chain regress), prep fusion (serialization
// regress), m97-gemm1 (role-diversity lesson), mod-3 role map (L2/slot
// regress) — all worse. This is the session's empirical optimum:
//   prep(4608): qk-proj + Wv^T + x->bf16
//   fused_gs(1536): gemm0 (m97-class) || softmax (attnB only), segment map
//   gemm1(256x512): 8-phase counted-vmcnt + attnF expansion on idle BW
// ---------------------------------------------------------------------------

typedef __attribute__((ext_vector_type(8))) __bf16 bf16x8;
typedef __attribute__((ext_vector_type(4))) __bf16 bf16x4;
typedef __attribute__((ext_vector_type(4))) float  f32x4;
typedef unsigned int u32;

#define GLB_CAST(p) ((const __attribute__((address_space(1))) u32*)(p))
#define LDS_CAST(p) ((__attribute__((address_space(3))) u32*)(p))

#define S_BARRIER() { __builtin_amdgcn_s_barrier(); __builtin_amdgcn_sched_barrier(0); }
#define LGKM0()     { asm volatile("s_waitcnt lgkmcnt(0)" ::: "memory"); __builtin_amdgcn_sched_barrier(0); }
#define VMCNT9()    { asm volatile("s_waitcnt vmcnt(9)" ::: "memory"); __builtin_amdgcn_sched_barrier(0); }
#define VMCNT8()    { asm volatile("s_waitcnt vmcnt(8)" ::: "memory"); __builtin_amdgcn_sched_barrier(0); }
#define VMCNT0()    { asm volatile("s_waitcnt vmcnt(0)" ::: "memory"); __builtin_amdgcn_sched_barrier(0); }

static constexpr int    Bn   = 8;
static constexpr int    S    = 2048;
static constexpr int    Dd   = 1024;
static constexpr int    Mtot = Bn * S;            // 16384
static constexpr size_t OUT0 = (size_t)Bn * S * Dd;

// workspace layout (bytes)
static constexpr size_t OFF_XBF  = 0;                                  // [16384][1024] bf16
static constexpr size_t OFF_WVT  = OFF_XBF + (size_t)Mtot * Dd * 2;    // [1024][1024] bf16 (Wv^T)
static constexpr size_t OFF_Q    = OFF_WVT + (size_t)Dd * Dd * 2;      // [16384][8] f32
static constexpr size_t OFF_K    = OFF_Q   + (size_t)Mtot * 8 * 4;     // [16384][8] f32
static constexpr size_t OFF_VT   = OFF_K   + (size_t)Mtot * 8 * 4;     // [8][1024][2048] bf16
static constexpr size_t OFF_ATTB = OFF_VT  + (size_t)Bn * Dd * S * 2;  // [8][2048][2048] bf16
static constexpr size_t WS_NEED  = OFF_ATTB + (size_t)Bn * S * S * 2;  // ~137 MB

// ---------------------------------------------------------------------------
// prep: blocks [0,256): q/k projection from f32 x, Wq, Wk (bf16 MFMA);
//       [256,512): Wv -> Wv^T bf16 ; [512,4608): x f32 -> bf16.
// ---------------------------------------------------------------------------
__global__ __launch_bounds__(256) void prep_kernel(
    const float* __restrict__ x, const float* __restrict__ Wq,
    const float* __restrict__ Wk, const float* __restrict__ Wv,
    const float* __restrict__ bq, const float* __restrict__ bk,
    __bf16* __restrict__ xbf, __bf16* __restrict__ wvt,
    float* __restrict__ qb, float* __restrict__ kb)
{
    __shared__ float lt[64][65];
    int bid = blockIdx.x, t = threadIdx.x;
    if (bid < 256) {
        int l = t & 63, w = t >> 6;
        int mbase = (bid * 4 + w) * 16;
        int n = l & 15;
        int dbase = (l >> 4) << 3;
        const float* xr = x + (size_t)(mbase + n) * 1024 + dbase;
        const float* wcol = (n < 8) ? (Wq + n) : (Wk + (n & 7));
        f32x4 acc = {0.f, 0.f, 0.f, 0.f};
        #pragma unroll 4
        for (int kk = 0; kk < 1024; kk += 32) {
            f32x4 a0 = *(const f32x4*)(xr + kk);
            f32x4 a1 = *(const f32x4*)(xr + kk + 4);
            bf16x8 a, b;
            #pragma unroll
            for (int c = 0; c < 4; ++c) { a[c] = (__bf16)a0[c]; a[4 + c] = (__bf16)a1[c]; }
            #pragma unroll
            for (int u = 0; u < 8; ++u) b[u] = (__bf16)wcol[(size_t)(dbase + kk + u) * 8];
            acc = __builtin_amdgcn_mfma_f32_16x16x32_bf16(a, b, acc, 0, 0, 0);
        }
        float bias = (n < 8) ? bq[n] : bk[n & 7];
        #pragma unroll
        for (int r = 0; r < 4; ++r) {
            int m = mbase + ((l >> 4) << 2) + r;
            float v = acc[r] + bias;
            if (n < 8) qb[m * 8 + n] = v;
            else       kb[m * 8 + (n & 7)] = v;
        }
    } else if (bid < 512) {
        int tile = bid - 256;
        int tr = tile >> 4, tc = tile & 15;
        int r0 = t >> 6, c = t & 63;
        #pragma unroll
        for (int i = 0; i < 16; ++i) {
            int row = i * 4 + r0;
            lt[row][c] = Wv[(size_t)(tr * 64 + row) * 1024 + tc * 64 + c];
        }
        __syncthreads();
        #pragma unroll
        for (int i = 0; i < 16; ++i) {
            int er = i * 4 + r0;
            wvt[(size_t)(tc * 64 + er) * 1024 + tr * 64 + c] = (__bf16)lt[c][er];
        }
    } else {
        int bid2 = bid - 512;
        #pragma unroll
        for (int i = 0; i < 4; ++i) {
            size_t idx4 = (size_t)i * 1048576 + (size_t)bid2 * 256 + t;
            f32x4 v = ((const f32x4*)x)[idx4];
            bf16x4 o;
            #pragma unroll
            for (int c = 0; c < 4; ++c) o[c] = (__bf16)v[c];
            ((bf16x4*)xbf)[idx4] = o;
        }
    }
}

// ---------------------------------------------------------------------------
// fused gemm0 || softmax. Grid 1536 x 256 threads.
// Segments of 256 blocks: 0=G,1=S,2=G,3=S,4=G,5=G (1024 gemm tiles, 512 sm
// chunks). gemm0: m97-class C[128(s)x128(e)], BK=64, 4 waves, single-buffer
// 32KB LDS, XOR swizzle; writes vt[b][e][s] bf16 + bias.
// softmax: writes ONLY attnB bf16 (attnF deferred to gemm1).
// ---------------------------------------------------------------------------
__global__ __launch_bounds__(256) void fused_gs_kernel(
    const __bf16* __restrict__ xbf, const __bf16* __restrict__ wvt,
    const float* __restrict__ bv,
    const float* __restrict__ qb, const float* __restrict__ kb,
    __bf16* __restrict__ vtOut, __bf16* __restrict__ attnB)
{
    __shared__ __align__(1024) char smem[32768];
    __shared__ float redm[4], reds[4];
    int bid = blockIdx.x, t = threadIdx.x;
    int seg = bid >> 8;
    int gid = -1, sid = -1;
    if (seg == 0) gid = bid;
    else if (seg == 1) sid = bid - 256;
    else if (seg == 2) gid = bid - 256;
    else if (seg == 3) sid = bid - 512;
    else gid = bid - 512;                        // segs 4,5 -> gid 512..1023

    if (sid < 0) {
        // ================= gemm0 (m97-class) =================
        int g = ((gid & 7) << 7) | (gid >> 3);   // bijective XCD swizzle (1024)
        int mblk = g >> 3, nblk = g & 7;         // 128 x 8
        int l = t & 63, wid = t >> 6;
        int wmr = wid >> 1, wnc = wid & 1;       // 2(M) x 2(N) waves
        int lr = l & 15, lk = l >> 4;

        int srow = t >> 3;                       // 0..31
        int ssl  = (t & 7) ^ (srow & 7);
        const __bf16* gA = xbf + (size_t)(mblk * 128 + srow) * 1024 + ssl * 8;
        const __bf16* gB = wvt + (size_t)(nblk * 128 + srow) * 1024 + ssl * 8;

        int s0 = (lk ^ (lr & 7)) << 3;
        int s1 = ((lk ^ 4) ^ (lr & 7)) << 3;
        int offA0 = (wmr * 64 + lr) * 64 + s0;
        int offA1 = (wmr * 64 + lr) * 64 + s1;
        int offB0 = (wnc * 64 + lr) * 64 + s0;
        int offB1 = (wnc * 64 + lr) * 64 + s1;

        f32x4 acc[4][4] = {};

        for (int tt = 0; tt < 16; ++tt) {
            int kk = tt * 64;
            #pragma unroll
            for (int c = 0; c < 4; ++c) {
                __builtin_amdgcn_global_load_lds(
                    GLB_CAST(gA + (size_t)c * 32 * 1024 + kk),
                    LDS_CAST(smem + c * 4096 + wid * 1024), 16, 0, 0);
                __builtin_amdgcn_global_load_lds(
                    GLB_CAST(gB + (size_t)c * 32 * 1024 + kk),
                    LDS_CAST(smem + 16384 + c * 4096 + wid * 1024), 16, 0, 0);
            }
            __syncthreads();
            const __bf16* As = (const __bf16*)smem;
            const __bf16* Bs = (const __bf16*)(smem + 16384);
            bf16x8 af[4], bfr[4];
            #pragma unroll
            for (int i = 0; i < 4; ++i) af[i]  = *(const bf16x8*)(As + offA0 + i * 1024);
            #pragma unroll
            for (int j = 0; j < 4; ++j) bfr[j] = *(const bf16x8*)(Bs + offB0 + j * 1024);
            #pragma unroll
            for (int i = 0; i < 4; ++i)
                #pragma unroll
                for (int j = 0; j < 4; ++j)
                    acc[i][j] = __builtin_amdgcn_mfma_f32_16x16x32_bf16(af[i], bfr[j], acc[i][j], 0, 0, 0);
            #pragma unroll
            for (int i = 0; i < 4; ++i) af[i]  = *(const bf16x8*)(As + offA1 + i * 1024);
            #pragma unroll
            for (int j = 0; j < 4; ++j) bfr[j] = *(const bf16x8*)(Bs + offB1 + j * 1024);
            #pragma unroll
            for (int i = 0; i < 4; ++i)
                #pragma unroll
                for (int j = 0; j < 4; ++j)
                    acc[i][j] = __builtin_amdgcn_mfma_f32_16x16x32_bf16(af[i], bfr[j], acc[i][j], 0, 0, 0);
            __syncthreads();
        }

        #pragma unroll
        for (int j = 0; j < 4; ++j) {
            int e = (nblk << 7) + wnc * 64 + j * 16 + lr;
            float bias = bv[e];
            #pragma unroll
            for (int i = 0; i < 4; ++i) {
                int m0 = (mblk << 7) + wmr * 64 + i * 16 + (lk << 2);
                int b = m0 >> 11, sA = m0 & 2047;
                bf16x4 o;
                #pragma unroll
                for (int r = 0; r < 4; ++r) o[r] = (__bf16)(acc[i][j][r] + bias);
                *(bf16x4*)&vtOut[(((size_t)(b << 10) + e) << 11) + sA] = o;
            }
        }
    } else {
        // ================= softmax (attnB only) =================
        int b = sid >> 6, chunk = sid & 63;
        int l = t & 63, w = t >> 6;
        float kr[8][8];
        const float* kbb = kb + ((size_t)b << 14);
        #pragma unroll
        for (int jj = 0; jj < 8; ++jj) {
            f32x4 v0 = *(const f32x4*)(kbb + (size_t)(t * 8 + jj) * 8);
            f32x4 v1 = *(const f32x4*)(kbb + (size_t)(t * 8 + jj) * 8 + 4);
            #pragma unroll
            for (int c = 0; c < 4; ++c) { kr[jj][c] = v0[c]; kr[jj][4 + c] = v1[c]; }
        }
        const float* qrow = qb + ((size_t)b << 14);
        for (int ii = 0; ii < 32; ++ii) {
            int i = (chunk << 5) + ii;
            f32x4 q0 = *(const f32x4*)(qrow + (size_t)i * 8);
            f32x4 q1 = *(const f32x4*)(qrow + (size_t)i * 8 + 4);
            float e[8];
            #pragma unroll
            for (int jj = 0; jj < 8; ++jj) {
                float s = q0[0] * kr[jj][0];
                s = fmaf(q0[1], kr[jj][1], s);
                s = fmaf(q0[2], kr[jj][2], s);
                s = fmaf(q0[3], kr[jj][3], s);
                s = fmaf(q1[0], kr[jj][4], s);
                s = fmaf(q1[1], kr[jj][5], s);
                s = fmaf(q1[2], kr[jj][6], s);
                s = fmaf(q1[3], kr[jj][7], s);
                e[jj] = s;
            }
            float mx = e[0];
            #pragma unroll
            for (int jj = 1; jj < 8; ++jj) mx = fmaxf(mx, e[jj]);
            #pragma unroll
            for (int d = 1; d < 64; d <<= 1) mx = fmaxf(mx, __shfl_xor(mx, d));
            if (l == 0) redm[w] = mx;
            __syncthreads();
            mx = fmaxf(fmaxf(redm[0], redm[1]), fmaxf(redm[2], redm[3]));
            float p[8], sum = 0.f;
            #pragma unroll
            for (int jj = 0; jj < 8; ++jj) { p[jj] = __expf(e[jj] - mx); sum += p[jj]; }
            #pragma unroll
            for (int d = 1; d < 64; d <<= 1) sum += __shfl_xor(sum, d);
            if (l == 0) reds[w] = sum;
            __syncthreads();
            float T = (reds[0] + reds[1]) + (reds[2] + reds[3]);
            float inv = 1.0f / T;
            size_t off = (((size_t)b << 11) + i) * 2048 + (size_t)t * 8;
            bf16x8 ob;
            #pragma unroll
            for (int c = 0; c < 4; ++c) {
                ob[c] = (__bf16)(p[c] * inv); ob[4 + c] = (__bf16)(p[4 + c] * inv);
            }
            *(bf16x8*)(attnB + off) = ob;
        }
    }
}

// ---------------------------------------------------------------------------
// gemm1 (8-phase) + interleaved attnB->attnF f32 expansion.
// Each block owns attnF rows [bb, mblk*256+nblk*64 .. +64); per K-iter tt:
// store chunk tt-2 (in pv), load chunk tt-1. vmcnt boundaries: tt==0 -> 8,
// tt>=1 -> 9 (8 staging + 1 copy-load; copy-stores are a full iter old).
// ---------------------------------------------------------------------------
__device__ __forceinline__ void g1_stageA(const __bf16* Ab, char* smem,
    int slot, int kk, int c, int rowin, int sl8, int wid)
{
    __builtin_amdgcn_global_load_lds(
        GLB_CAST(Ab + (size_t)(c * 64 + rowin) * 2048 + kk + sl8 * 8),
        LDS_CAST(smem + slot * 65536 + c * 8192 + wid * 1024), 16, 0, 0);
}
__device__ __forceinline__ void g1_stageB(const __bf16* Bb, char* smem,
    int slot, int kk, int c, int rowin, int sl8, int wid)
{
    __builtin_amdgcn_global_load_lds(
        GLB_CAST(Bb + (size_t)(c * 64 + rowin) * 2048 + kk + sl8 * 8),
        LDS_CAST(smem + slot * 65536 + 32768 + c * 8192 + wid * 1024), 16, 0, 0);
}

__global__ __launch_bounds__(512, 2) void gemm1_kernel(
    const __bf16* __restrict__ A, const __bf16* __restrict__ Bt,
    float* __restrict__ outF, float* __restrict__ attnF)
{
    constexpr int NT = 32;
    __shared__ __align__(1024) char smem[131072];

    int bid = blockIdx.x;
    int wg = ((bid & 7) << 5) | (bid >> 3);     // bijective XCD swizzle (nwg=256)
    int t = threadIdx.x, l = t & 63;
    int wid = t >> 6;
    int wmr = wid >> 2, wnc = wid & 3;

    int bb = wg >> 5; int r = wg & 31;          // one batch per XCD
    int mblk = r >> 2, nblk = r & 3;
    const __bf16* Ab = A + (size_t)bb * S * S + (size_t)mblk * 256 * 2048;
    const __bf16* Bb = Bt + (size_t)bb * Dd * S + (size_t)nblk * 256 * 2048;

    int rowin = t >> 3;
    int sl8 = (t & 7) ^ (rowin & 7);
    int lr = l & 15, lk = l >> 4;

    // attnF copy-role: row slice nblk*64 + (t>>3), col chunk (t&7)*8
    int crow = nblk * 64 + (t >> 3);
    int ccol = (t & 7) * 8;
    const __bf16* cpSrc = Ab + (size_t)crow * 2048 + ccol;
    float* cpDst = attnF + ((size_t)bb << 22) + ((size_t)(mblk * 256 + crow) << 11) + ccol;
    bf16x8 pv;

    f32x4 acc[8][4] = {};

    #pragma unroll
    for (int c = 0; c < 4; ++c) {
        g1_stageA(Ab, smem, 0, 0, c, rowin, sl8, wid);
        g1_stageB(Bb, smem, 0, 0, c, rowin, sl8, wid);
    }
    #pragma unroll
    for (int c = 0; c < 4; ++c) {
        g1_stageA(Ab, smem, 1, 64, c, rowin, sl8, wid);
        g1_stageB(Bb, smem, 1, 64, c, rowin, sl8, wid);
    }
    VMCNT8();
    S_BARRIER();

    for (int tt = 0; tt < NT; ++tt) {
        int s = tt & 1;
        const __bf16* Asl = (const __bf16*)(smem + s * 65536);
        const __bf16* Bsl = (const __bf16*)(smem + s * 65536 + 32768);
        bool pf = (tt + 2 < NT);
        int kk2 = (tt + 2) * 64;

        // ---- interleaved attnF copy: store chunk tt-2, load chunk tt-1
        if (tt >= 2) {
            f32x4 c0, c1;
            #pragma unroll
            for (int c = 0; c < 4; ++c) { c0[c] = (float)pv[c]; c1[c] = (float)pv[4 + c]; }
            *(f32x4*)(cpDst + (tt - 2) * 64) = c0;
            *(f32x4*)(cpDst + (tt - 2) * 64 + 4) = c1;
        }
        if (tt >= 1) {
            pv = *(const bf16x8*)(cpSrc + (tt - 1) * 64);
        }

        bf16x8 aLo[2][4], aHi[2][4], bLo[2][2], bHi[2][2];

        // ---- P0
        #pragma unroll
        for (int ks = 0; ks < 2; ++ks) {
            int sa = ks * 4 + lk;
            #pragma unroll
            for (int i = 0; i < 4; ++i) {
                int ra = wmr * 128 + i * 16 + lr;
                aLo[ks][i] = *(const bf16x8*)&Asl[ra * 64 + ((sa ^ (ra & 7)) << 3)];
            }
            #pragma unroll
            for (int j = 0; j < 2; ++j) {
                int rb = wnc * 64 + j * 16 + lr;
                bLo[ks][j] = *(const bf16x8*)&Bsl[rb * 64 + ((sa ^ (rb & 7)) << 3)];
            }
        }
        S_BARRIER(); LGKM0();
        __builtin_amdgcn_s_setprio(1);
        #pragma unroll
        for (int ks = 0; ks < 2; ++ks)
            #pragma unroll
            for (int i = 0; i < 4; ++i)
                #pragma unroll
                for (int j = 0; j < 2; ++j)
                    acc[i][j] = __builtin_amdgcn_mfma_f32_16x16x32_bf16(aLo[ks][i], bLo[ks][j], acc[i][j], 0, 0, 0);
        __builtin_amdgcn_s_setprio(0);
        S_BARRIER();

        // ---- P1
        #pragma unroll
        for (int ks = 0; ks < 2; ++ks) {
            int sa = ks * 4 + lk;
            #pragma unroll
            for (int j = 0; j < 2; ++j) {
                int rb = wnc * 64 + (j + 2) * 16 + lr;
                bHi[ks][j] = *(const bf16x8*)&Bsl[rb * 64 + ((sa ^ (rb & 7)) << 3)];
            }
        }
        if (pf) {
            g1_stageA(Ab, smem, s, kk2, 0, rowin, sl8, wid);
            g1_stageA(Ab, smem, s, kk2, 2, rowin, sl8, wid);
        }
        S_BARRIER(); LGKM0();
        __builtin_amdgcn_s_setprio(1);
        #pragma unroll
        for (int ks = 0; ks < 2; ++ks)
            #pragma unroll
            for (int i = 0; i < 4; ++i)
                #pragma unroll
                for (int j = 0; j < 2; ++j)
                    acc[i][2 + j] = __builtin_amdgcn_mfma_f32_16x16x32_bf16(aLo[ks][i], bHi[ks][j], acc[i][2 + j], 0, 0, 0);
        __builtin_amdgcn_s_setprio(0);
        S_BARRIER();

        // ---- P2
        #pragma unroll
        for (int ks = 0; ks < 2; ++ks) {
            int sa = ks * 4 + lk;
            #pragma unroll
            for (int i = 0; i < 4; ++i) {
                int ra = wmr * 128 + (i + 4) * 16 + lr;
                aHi[ks][i] = *(const bf16x8*)&Asl[ra * 64 + ((sa ^ (ra & 7)) << 3)];
            }
        }
        if (pf) {
            #pragma unroll
            for (int c = 0; c < 4; ++c)
                g1_stageB(Bb, smem, s, kk2, c, rowin, sl8, wid);
        }
        S_BARRIER(); LGKM0();
        __builtin_amdgcn_s_setprio(1);
        #pragma unroll
        for (int ks = 0; ks < 2; ++ks)
            #pragma unroll
            for (int i = 0; i < 4; ++i)
                #pragma unroll
                for (int j = 0; j < 2; ++j)
                    acc[4 + i][2 + j] = __builtin_amdgcn_mfma_f32_16x16x32_bf16(aHi[ks][i], bHi[ks][j], acc[4 + i][2 + j], 0, 0, 0);
        __builtin_amdgcn_s_setprio(0);
        S_BARRIER();

        // ---- P3
        if (pf) {
            g1_stageA(Ab, smem, s, kk2, 1, rowin, sl8, wid);
            g1_stageA(Ab, smem, s, kk2, 3, rowin, sl8, wid);
        }
        S_BARRIER();
        __builtin_amdgcn_s_setprio(1);
        #pragma unroll
        for (int ks = 0; ks < 2; ++ks)
            #pragma unroll
            for (int i = 0; i < 4; ++i)
                #pragma unroll
                for (int j = 0; j < 2; ++j)
                    acc[4 + i][j] = __builtin_amdgcn_mfma_f32_16x16x32_bf16(aHi[ks][i], bLo[ks][j], acc[4 + i][j], 0, 0, 0);
        __builtin_amdgcn_s_setprio(0);

        if (tt == NT - 1) break;
        S_BARRIER();
        if (pf) {
            if (tt == 0) { VMCNT8(); } else { VMCNT9(); }
        } else {
            VMCNT0();
        }
        S_BARRIER();
    }

    // ---- finish attnF chunks NT-2 (in pv) and NT-1
    {
        f32x4 c0, c1;
        #pragma unroll
        for (int c = 0; c < 4; ++c) { c0[c] = (float)pv[c]; c1[c] = (float)pv[4 + c]; }
        *(f32x4*)(cpDst + (NT - 2) * 64) = c0;
        *(f32x4*)(cpDst + (NT - 2) * 64 + 4) = c1;
        bf16x8 lastv = *(const bf16x8*)(cpSrc + (NT - 1) * 64);
        #pragma unroll
        for (int c = 0; c < 4; ++c) { c0[c] = (float)lastv[c]; c1[c] = (float)lastv[4 + c]; }
        *(f32x4*)(cpDst + (NT - 1) * 64) = c0;
        *(f32x4*)(cpDst + (NT - 1) * 64 + 4) = c1;
    }

    float* ob = outF + (size_t)bb * S * Dd;
    #pragma unroll
    for (int i = 0; i < 8; ++i) {
        int m0 = (mblk << 8) + wmr * 128 + i * 16 + (lk << 2);
        #pragma unroll
        for (int j = 0; j < 4; ++j) {
            int e = (nblk << 8) + wnc * 64 + j * 16 + lr;
            #pragma unroll
            for (int r = 0; r < 4; ++r)
                ob[(size_t)(m0 + r) * 1024 + e] = acc[i][j][r];
        }
    }
}

// ---------------------------------------------------------------------------
extern "C" void kernel_launch(void* const* d_in, const int* in_sizes, int n_in,
                              void* d_out, int out_size, void* d_ws, size_t ws_size,
                              hipStream_t stream)
{
    const float* x  = (const float*)d_in[0];
    const float* Wq = (const float*)d_in[1];
    const float* bq = (const float*)d_in[2];
    const float* Wk = (const float*)d_in[3];
    const float* bk = (const float*)d_in[4];
    const float* Wv = (const float*)d_in[5];
    const float* bv = (const float*)d_in[6];

    float* outp  = (float*)d_out;
    float* attnF = outp + OUT0;

    if (ws_size < WS_NEED) return;
    char* ws = (char*)d_ws;
    __bf16* xbf   = (__bf16*)(ws + OFF_XBF);
    __bf16* wvt   = (__bf16*)(ws + OFF_WVT);
    float*  qbuf  = (float*)(ws + OFF_Q);
    float*  kbuf  = (float*)(ws + OFF_K);
    __bf16* vt    = (__bf16*)(ws + OFF_VT);
    __bf16* attnB = (__bf16*)(ws + OFF_ATTB);

    prep_kernel<<<4608, 256, 0, stream>>>(x, Wq, Wk, Wv, bq, bk, xbf, wvt, qbuf, kbuf);
    fused_gs_kernel<<<1536, 256, 0, stream>>>(xbf, wvt, bv, qbuf, kbuf, vt, attnB);
    gemm1_kernel<<<256, 512, 0, stream>>>(attnB, vt, outp, attnF);
}